// Round 14
// baseline (1122.152 us; speedup 1.0000x reference)
//
#include <hip/hip_runtime.h>

#define N_NODES 20000
#define N_PAD   20096      /* 157*128 */
#define N_EDGES 320000
#define F_IN 4644
#define KP0  4672          /* F_IN padded to 32 */
#define NP2  4736          /* F_IN padded to 128 */
#define F_H 512
#define EPSV 1e-5f
#define SZL 10240000L
#define ACT 5200000L

using short8 = __attribute__((ext_vector_type(8))) short;
using f32x4  = __attribute__((ext_vector_type(4))) float;

__device__ inline unsigned short f2b(float f){
  union{float f; unsigned u;} v; v.f=f;
  unsigned u = v.u + 0x7fffu + ((v.u>>16)&1u);
  return (unsigned short)(u>>16);
}
__device__ inline float blo(unsigned v){ return __uint_as_float(v<<16); }
__device__ inline float bhi(unsigned v){ return __uint_as_float(v & 0xffff0000u); }
__device__ inline float b2f(unsigned short v){ return __uint_as_float(((unsigned)v)<<16); }

#define GLDS(g, l) __builtin_amdgcn_global_load_lds( \
    (const __attribute__((address_space(1))) void*)(g), \
    (__attribute__((address_space(3))) void*)(l), 16, 0, 0)

// ---------------- utility / CSR ----------------
__global__ void k_zero_ds(int* __restrict__ deg, float* __restrict__ st){
  int i = blockIdx.x*blockDim.x+threadIdx.x;
  if (i < N_NODES) deg[i] = 0;
  else if (i < N_NODES + 3072) st[i - N_NODES] = 0.f;
}
__global__ void k_degree(const int* __restrict__ dst, int* __restrict__ deg){
  int e = blockIdx.x*blockDim.x+threadIdx.x;
  if (e < N_EDGES) atomicAdd(&deg[dst[e]], 1);
}
__global__ __launch_bounds__(1024) void k_scan(const int* __restrict__ deg, int* __restrict__ rowptr,
                                               int* __restrict__ cursor, float* __restrict__ dinv){
  __shared__ int sh[1024];
  int t = threadIdx.x;
  const int C = 20;
  int base = t*C;
  int loc[C];
  int s = 0;
  #pragma unroll
  for (int i=0;i<C;i++){ int idx=base+i; int v = (idx<N_NODES)?deg[idx]:0; loc[i]=s; s+=v; }
  sh[t]=s; __syncthreads();
  for (int off=1; off<1024; off<<=1){
    int v = (t>=off)?sh[t-off]:0;
    __syncthreads();
    sh[t]+=v;
    __syncthreads();
  }
  int excl = (t==0)?0:sh[t-1];
  #pragma unroll
  for (int i=0;i<C;i++){
    int idx=base+i;
    if(idx<N_NODES){
      int rv = excl+loc[i];
      rowptr[idx]=rv; cursor[idx]=rv;
      dinv[idx] = rsqrtf((float)(deg[idx]+1));
    }
  }
  if (t==1023) rowptr[N_NODES]=sh[1023];
}
__global__ void k_scatter(const int* __restrict__ src, const int* __restrict__ dst,
                          int* __restrict__ cursor, int* __restrict__ colsrc){
  int e = blockIdx.x*blockDim.x+threadIdx.x;
  if (e < N_EDGES){
    int p = atomicAdd(&cursor[dst[e]], 1);
    colsrc[p] = src[e];
  }
}

// ---------------- weight conversions (one launch) ----------------
__global__ void k_cvtW(const float* __restrict__ W0, const float* __restrict__ W1,
                       const float* __restrict__ W2, const float* __restrict__ L1,
                       const float* __restrict__ L2,
                       unsigned short* __restrict__ W0T, unsigned short* __restrict__ W1T,
                       unsigned short* __restrict__ W2T, unsigned short* __restrict__ l1WT,
                       unsigned short* __restrict__ l2WT){
  long t = (long)blockIdx.x*256 + threadIdx.x;
  const long n0 = (long)F_H*KP0;
  const long nh = (long)F_H*F_H;
  const long n2 = (long)NP2*F_H;
  if (t < n0) {
    int n = (int)(t / KP0), k = (int)(t % KP0);
    W0T[t] = f2b(k < F_IN ? W0[(long)k*F_H + n] : 0.f);
  } else if ((t -= n0) < nh) {
    int n = (int)(t / F_H), k = (int)(t % F_H);
    W1T[t] = f2b(W1[(long)k*F_H + n]);
  } else if ((t -= nh) < nh) {
    int n = (int)(t / F_H), k = (int)(t % F_H);
    W2T[t] = f2b(W2[(long)k*F_H + n]);
  } else if ((t -= nh) < nh) {
    int n = (int)(t / F_H), k = (int)(t % F_H);
    l1WT[t] = f2b(L1[(long)k*F_H + n]);
  } else if ((t -= nh) < n2) {
    int n = (int)(t / F_H), k = (int)(t % F_H);
    l2WT[t] = f2b(n < F_IN ? L2[(long)k*F_IN + n] : 0.f);
  }
}

// ---------------- k_gbx: conv0 with fused fp32->bf16 A conversion ----------------
// C[M,512] = x[M,4644](fp32) @ W0T[512,4672](bf16)^T, bf16 out.
// A staged RAW fp32 via GLDS (async path preserved; 4 GLDS/wave/iter), converted to bf16
// on the LDS->reg read path with v_cvt_pk_bf16_f32 (overlaps MFMA). Row-clamp for M-tail
// (legal reads, outputs discarded); K-tail clamp reads finite data x zero-padded B = 0.
// LDS: A fp32 [128][32] x2 (8 slots/row, slot ^= row&7 swizzle -> 2-way banks), B as k_gb.
__global__ __launch_bounds__(256) void k_gbx(
    const float* __restrict__ X, const unsigned short* __restrict__ BT,
    unsigned short* __restrict__ C)
{
  __shared__ float          AsF[2][4096];   // 16 KB each
  __shared__ unsigned short Bs [2][4096];   // 8 KB each
  const int tid  = threadIdx.x;
  const int gx   = gridDim.x;                       // 4
  const int nwg  = gx * gridDim.y;                  // 628
  const int orig = blockIdx.x + gx * blockIdx.y;
  const int q = nwg >> 3, r = nwg & 7;
  const int xcd = orig & 7, sub = orig >> 3;
  const int wg  = (xcd < r ? xcd*(q+1) : r*(q+1) + (xcd - r)*q) + sub;
  const int bn  = (wg % gx) * 128;
  const int bm  = (wg / gx) * 128;
  const int wave = tid >> 6, lane = tid & 63;
  const int wm = (wave & 1) * 64, wn = (wave >> 1) * 64;
  const int l15 = lane & 15, l4 = lane >> 4;

  f32x4 acc[4][4];
  #pragma unroll
  for (int m=0;m<4;m++)
    #pragma unroll
    for (int n=0;n<4;n++) acc[m][n] = (f32x4){0.f,0.f,0.f,0.f};

  // A: 1024 16B-chunks/tile; chunk c -> row c>>3, dest slot c&7; src col-chunk = slot^(row&7)
  long arowA[4]; int acolq[4]; int adst[4];
  #pragma unroll
  for (int j=0;j<4;j++){
    int c = j*256 + wave*64 + lane;
    int rowj = c >> 3, slotj = c & 7;
    long ar = bm + rowj; if (ar > N_NODES-1) ar = N_NODES-1;
    arowA[j] = ar;
    acolq[j] = (slotj ^ (rowj & 7)) * 4;          // float offset within K-step
    adst[j]  = (j*256 + wave*64) * 4;             // float offset, wave-uniform
  }
  // B: 512 16B-chunks/tile (bf16); as k_gb
  const int c0 = wave*64 + lane;
  const int c1 = c0 + 256;
  const long br0 = bn + (c0 >> 2); const int bs0 = ((c0 & 3) ^ ((c0 >> 3) & 3))*8;
  const long br1 = bn + (c1 >> 2); const int bs1 = ((c1 & 3) ^ ((c1 >> 3) & 3))*8;
  const int ldB0 = wave*512;
  const int ldB1 = 2048 + wave*512;

  const int kroB = (l4 ^ ((l15 >> 1) & 3)) * 8;   // B read swizzle (ushort offset)
  const int nit = KP0 >> 5;                       // 146

  auto stageA = [&](int buf, int k0){
    #pragma unroll
    for (int j=0;j<4;j++){
      int col = k0 + acolq[j];
      if (col > F_IN - 4) col = F_IN - 4;         // K-tail: finite data x zero B
      GLDS(X + arowA[j]*F_IN + col, &AsF[buf][adst[j]]);
    }
  };
  auto stageB = [&](int buf, int k0){
    GLDS(BT + br0*KP0 + (k0 + bs0), &Bs[buf][ldB0]);
    GLDS(BT + br1*KP0 + (k0 + bs1), &Bs[buf][ldB1]);
  };

  stageA(0, 0); stageB(0, 0);
  __syncthreads();

  int cur = 0;
  for (int it = 0; it < nit; ++it) {
    if (it + 1 < nit) { stageA(cur^1, (it+1)*32); stageB(cur^1, (it+1)*32); }

    short8 af[4], bf[4];
    #pragma unroll
    for (int m=0;m<4;m++){
      int rr = wm + m*16 + l15;
      int s0 = (2*l4) ^ (rr & 7);                 // slot holding col-chunk 2*l4
      f32x4 lo = *(f32x4*)&AsF[cur][rr*32 + s0*4];
      f32x4 hi = *(f32x4*)&AsF[cur][rr*32 + (s0^1)*4];
      unsigned u0,u1,u2,u3;
      asm("v_cvt_pk_bf16_f32 %0, %1, %2" : "=v"(u0) : "v"(lo[0]), "v"(lo[1]));
      asm("v_cvt_pk_bf16_f32 %0, %1, %2" : "=v"(u1) : "v"(lo[2]), "v"(lo[3]));
      asm("v_cvt_pk_bf16_f32 %0, %1, %2" : "=v"(u2) : "v"(hi[0]), "v"(hi[1]));
      asm("v_cvt_pk_bf16_f32 %0, %1, %2" : "=v"(u3) : "v"(hi[2]), "v"(hi[3]));
      union { unsigned u[4]; short8 s; } pk;
      pk.u[0]=u0; pk.u[1]=u1; pk.u[2]=u2; pk.u[3]=u3;
      af[m] = pk.s;
    }
    #pragma unroll
    for (int n=0;n<4;n++) bf[n] = *(const short8*)&Bs[cur][(wn + n*16 + l15)*32 + kroB];
    #pragma unroll
    for (int m=0;m<4;m++)
      #pragma unroll
      for (int n=0;n<4;n++)
        acc[m][n] = __builtin_amdgcn_mfma_f32_16x16x32_bf16(af[m], bf[n], acc[m][n], 0, 0, 0);

    __syncthreads();
    cur ^= 1;
  }

  // ---- epilogue (bf16 out, ldc = F_H); reuse AsF as fp32 scratch ----
  float* eb = ((float*)AsF) + wave*1088;
  #pragma unroll
  for (int m=0;m<4;m++){
    #pragma unroll
    for (int n=0;n<4;n++)
      #pragma unroll
      for (int r2=0;r2<4;r2++)
        eb[(l4*4+r2)*68 + n*16 + l15] = acc[m][n][r2];
    __syncthreads();
    const int row0 = bm + wm + m*16;
    #pragma unroll
    for (int i=0;i<4;i++){
      int idx = i*64 + lane;
      int rr  = idx >> 4;
      int c4  = (idx & 15) * 4;
      int row = row0 + rr;
      int col = bn + wn + c4;
      if (row < N_NODES) {
        f32x4 v = *(f32x4*)&eb[rr*68 + c4];
        unsigned short o[4] = { f2b(v[0]), f2b(v[1]), f2b(v[2]), f2b(v[3]) };
        *(uint2*)&C[(long)row*F_H + col] = *(uint2*)o;
      }
    }
    __syncthreads();
  }
}

// ---------------- k_gb: 2-buffer GLDS dbuf (lin2) ----------------
template<int OUTB, int RELU, int NTS>
__global__ __launch_bounds__(256) void k_gb(
    const unsigned short* __restrict__ A, const unsigned short* __restrict__ BT,
    const float* __restrict__ bias, void* __restrict__ Cvoid,
    int M, int N, int KP, int lda, int ldc)
{
  __shared__ unsigned short smem[4][4096];
  const int tid  = threadIdx.x;
  const int gx   = gridDim.x;
  const int nwg  = gx * gridDim.y;
  const int orig = blockIdx.x + gx * blockIdx.y;
  const int q = nwg >> 3, r = nwg & 7;
  const int xcd = orig & 7, sub = orig >> 3;
  const int wg  = (xcd < r ? xcd*(q+1) : r*(q+1) + (xcd - r)*q) + sub;
  const int bn  = (wg % gx) * 128;
  const int bm  = (wg / gx) * 128;
  const int wave = tid >> 6, lane = tid & 63;
  const int wm = (wave & 1) * 64, wn = (wave >> 1) * 64;
  const int l15 = lane & 15, l4 = lane >> 4;

  f32x4 acc[4][4];
  #pragma unroll
  for (int m=0;m<4;m++)
    #pragma unroll
    for (int n=0;n<4;n++) acc[m][n] = (f32x4){0.f,0.f,0.f,0.f};

  const int c0 = wave*64 + lane;
  const int c1 = c0 + 256;
  const long ar0 = bm + (c0 >> 2); const int as0 = ((c0 & 3) ^ ((c0 >> 3) & 3))*8;
  const long ar1 = bm + (c1 >> 2); const int as1 = ((c1 & 3) ^ ((c1 >> 3) & 3))*8;
  const long br0 = bn + (c0 >> 2);
  const long br1 = bn + (c1 >> 2);
  const int ldA0 = wave*512;
  const int ldA1 = 2048 + wave*512;
  const int kro = (l4 ^ ((l15 >> 1) & 3)) * 8;
  const int nit = KP >> 5;

  GLDS(A + ar0*lda + as0, &smem[0][ldA0]);
  GLDS(A + ar1*lda + as1, &smem[0][ldA1]);
  GLDS(BT + br0*KP + as0, &smem[2][ldA0]);
  GLDS(BT + br1*KP + as1, &smem[2][ldA1]);
  __syncthreads();

  int cur = 0;
  for (int it = 0; it < nit; ++it) {
    if (it + 1 < nit) {
      const int kn = (it+1)*32;
      GLDS(A + ar0*lda + (kn + as0), &smem[cur^1][ldA0]);
      GLDS(A + ar1*lda + (kn + as1), &smem[cur^1][ldA1]);
      GLDS(BT + br0*KP + (kn + as0), &smem[2+(cur^1)][ldA0]);
      GLDS(BT + br1*KP + (kn + as1), &smem[2+(cur^1)][ldA1]);
    }
    short8 af[4], bf[4];
    #pragma unroll
    for (int m=0;m<4;m++) af[m] = *(const short8*)&smem[cur][(wm + m*16 + l15)*32 + kro];
    #pragma unroll
    for (int n=0;n<4;n++) bf[n] = *(const short8*)&smem[2+cur][(wn + n*16 + l15)*32 + kro];
    #pragma unroll
    for (int m=0;m<4;m++)
      #pragma unroll
      for (int n=0;n<4;n++)
        acc[m][n] = __builtin_amdgcn_mfma_f32_16x16x32_bf16(af[m], bf[n], acc[m][n], 0, 0, 0);
    __syncthreads();
    cur ^= 1;
  }

  float* eb = ((float*)smem) + wave*1088;
  float* Cf = (float*)Cvoid;
  unsigned short* Cb = (unsigned short*)Cvoid;
  #pragma unroll
  for (int m=0;m<4;m++){
    #pragma unroll
    for (int n=0;n<4;n++)
      #pragma unroll
      for (int r2=0;r2<4;r2++)
        eb[(l4*4+r2)*68 + n*16 + l15] = acc[m][n][r2];
    __syncthreads();
    const int row0 = bm + wm + m*16;
    #pragma unroll
    for (int i=0;i<4;i++){
      int idx = i*64 + lane;
      int rr  = idx >> 4;
      int c4  = (idx & 15) * 4;
      int row = row0 + rr;
      int col = bn + wn + c4;
      if (row < M) {
        f32x4 v = *(f32x4*)&eb[rr*68 + c4];
        float vv[4] = {v[0], v[1], v[2], v[3]};
        if (col + 3 < N) {
          #pragma unroll
          for (int j=0;j<4;j++){
            float zz = vv[j] + (bias ? bias[col+j] : 0.f);
            vv[j] = RELU ? fmaxf(zz, 0.f) : zz;
          }
          if (OUTB) {
            unsigned short o[4] = { f2b(vv[0]), f2b(vv[1]), f2b(vv[2]), f2b(vv[3]) };
            *(uint2*)&Cb[(long)row*ldc + col] = *(uint2*)o;
          } else {
            f32x4 ov = {vv[0], vv[1], vv[2], vv[3]};
            if (NTS) __builtin_nontemporal_store(ov, (f32x4*)&Cf[(long)row*ldc + col]);
            else     *(f32x4*)&Cf[(long)row*ldc + col] = ov;
          }
        } else {
          #pragma unroll
          for (int j=0;j<4;j++){
            int cc = col + j;
            if (cc < N) {
              float zz = vv[j] + (bias ? bias[cc] : 0.f);
              if (RELU) zz = fmaxf(zz, 0.f);
              if (OUTB) Cb[(long)row*ldc + cc] = f2b(zz);
              else if (NTS) __builtin_nontemporal_store(zz, &Cf[(long)row*ldc + cc]);
              else     Cf[(long)row*ldc + cc] = zz;
            }
          }
        }
      }
    }
    __syncthreads();
  }
}

// ---------------- k_gb3: 3-buffer counted-vmcnt (grid-limited bf16-A GEMMs) ----------------
template<int OUTB, int RELU>
__global__ __launch_bounds__(256) void k_gb3(
    const unsigned short* __restrict__ A, const unsigned short* __restrict__ BT,
    const float* __restrict__ bias, void* __restrict__ Cvoid,
    int M, int N, int KP, int lda, int ldc)
{
  __shared__ unsigned short smem[6][4096];
  const int tid  = threadIdx.x;
  const int gx   = gridDim.x;
  const int nwg  = gx * gridDim.y;
  const int orig = blockIdx.x + gx * blockIdx.y;
  const int q = nwg >> 3, r = nwg & 7;
  const int xcd = orig & 7, sub = orig >> 3;
  const int wg  = (xcd < r ? xcd*(q+1) : r*(q+1) + (xcd - r)*q) + sub;
  const int bn  = (wg % gx) * 128;
  const int bm  = (wg / gx) * 128;
  const int wave = tid >> 6, lane = tid & 63;
  const int wm = (wave & 1) * 64, wn = (wave >> 1) * 64;
  const int l15 = lane & 15, l4 = lane >> 4;

  f32x4 acc[4][4];
  #pragma unroll
  for (int m=0;m<4;m++)
    #pragma unroll
    for (int n=0;n<4;n++) acc[m][n] = (f32x4){0.f,0.f,0.f,0.f};

  const int c0 = wave*64 + lane;
  const int c1 = c0 + 256;
  const long ar0 = bm + (c0 >> 2); const int as0 = ((c0 & 3) ^ ((c0 >> 3) & 3))*8;
  const long ar1 = bm + (c1 >> 2); const int as1 = ((c1 & 3) ^ ((c1 >> 3) & 3))*8;
  const long br0 = bn + (c0 >> 2);
  const long br1 = bn + (c1 >> 2);
  const int ldA0 = wave*512;
  const int ldA1 = 2048 + wave*512;
  const int kro = (l4 ^ ((l15 >> 1) & 3)) * 8;
  const int nit = KP >> 5;

  GLDS(A + ar0*lda + as0, &smem[0][ldA0]);
  GLDS(A + ar1*lda + as1, &smem[0][ldA1]);
  GLDS(BT + br0*KP + as0, &smem[3][ldA0]);
  GLDS(BT + br1*KP + as1, &smem[3][ldA1]);
  if (nit > 1) {
    GLDS(A + ar0*lda + 32 + as0, &smem[1][ldA0]);
    GLDS(A + ar1*lda + 32 + as1, &smem[1][ldA1]);
    GLDS(BT + br0*KP + 32 + as0, &smem[4][ldA0]);
    GLDS(BT + br1*KP + 32 + as1, &smem[4][ldA1]);
  }

  int cur = 0, pre = 2;
  for (int it = 0; it < nit; ++it) {
    if (it + 1 < nit) asm volatile("s_waitcnt vmcnt(4)" ::: "memory");
    else              asm volatile("s_waitcnt vmcnt(0)" ::: "memory");
    __builtin_amdgcn_s_barrier();

    if (it + 2 < nit) {
      const int kn = (it+2)*32;
      GLDS(A + ar0*lda + (kn + as0), &smem[pre][ldA0]);
      GLDS(A + ar1*lda + (kn + as1), &smem[pre][ldA1]);
      GLDS(BT + br0*KP + (kn + as0), &smem[3+pre][ldA0]);
      GLDS(BT + br1*KP + (kn + as1), &smem[3+pre][ldA1]);
    }

    short8 af[4], bf[4];
    #pragma unroll
    for (int m=0;m<4;m++) af[m] = *(const short8*)&smem[cur][(wm + m*16 + l15)*32 + kro];
    #pragma unroll
    for (int n=0;n<4;n++) bf[n] = *(const short8*)&smem[3+cur][(wn + n*16 + l15)*32 + kro];
    #pragma unroll
    for (int m=0;m<4;m++)
      #pragma unroll
      for (int n=0;n<4;n++)
        acc[m][n] = __builtin_amdgcn_mfma_f32_16x16x32_bf16(af[m], bf[n], acc[m][n], 0, 0, 0);

    cur = (cur == 2) ? 0 : cur + 1;
    pre = (pre == 2) ? 0 : pre + 1;
  }
  __syncthreads();

  float* eb = ((float*)smem) + wave*1088;
  float* Cf = (float*)Cvoid;
  unsigned short* Cb = (unsigned short*)Cvoid;
  #pragma unroll
  for (int m=0;m<4;m++){
    #pragma unroll
    for (int n=0;n<4;n++)
      #pragma unroll
      for (int r2=0;r2<4;r2++)
        eb[(l4*4+r2)*68 + n*16 + l15] = acc[m][n][r2];
    __syncthreads();
    const int row0 = bm + wm + m*16;
    #pragma unroll
    for (int i=0;i<4;i++){
      int idx = i*64 + lane;
      int rr  = idx >> 4;
      int c4  = (idx & 15) * 4;
      int row = row0 + rr;
      int col = bn + wn + c4;
      if (row < M) {
        f32x4 v = *(f32x4*)&eb[rr*68 + c4];
        float vv[4] = {v[0], v[1], v[2], v[3]};
        if (col + 3 < N) {
          #pragma unroll
          for (int j=0;j<4;j++){
            float zz = vv[j] + (bias ? bias[col+j] : 0.f);
            vv[j] = RELU ? fmaxf(zz, 0.f) : zz;
          }
          if (OUTB) {
            unsigned short o[4] = { f2b(vv[0]), f2b(vv[1]), f2b(vv[2]), f2b(vv[3]) };
            *(uint2*)&Cb[(long)row*ldc + col] = *(uint2*)o;
          } else {
            *(f32x4*)&Cf[(long)row*ldc + col] = (f32x4){vv[0], vv[1], vv[2], vv[3]};
          }
        } else {
          #pragma unroll
          for (int j=0;j<4;j++){
            int cc = col + j;
            if (cc < N) {
              float zz = vv[j] + (bias ? bias[cc] : 0.f);
              if (RELU) zz = fmaxf(zz, 0.f);
              if (OUTB) Cb[(long)row*ldc + cc] = f2b(zz);
              else      Cf[(long)row*ldc + cc] = zz;
            }
          }
        }
      }
    }
    __syncthreads();
  }
}

// ---------------- GCN aggregation ----------------
__global__ __launch_bounds__(256) void k_agg(const unsigned short* __restrict__ h,
    const int* __restrict__ rowptr, const int* __restrict__ colsrc,
    const float* __restrict__ dinv, const float* __restrict__ bias,
    float* __restrict__ out)
{
  int d = blockIdx.x;
  int t = threadIdx.x;
  const unsigned* h32 = (const unsigned*)h;
  float di = dinv[d];
  int beg = rowptr[d], end = rowptr[d+1];
  float a0 = 0.f, a1 = 0.f;
  for (int e = beg; e < end; e++) {
    int s = colsrc[e];
    float cf = dinv[s]*di;
    unsigned v = h32[(long)s*256 + t];
    a0 += blo(v)*cf;
    a1 += bhi(v)*cf;
  }
  unsigned v = h32[(long)d*256 + t];
  float sc = di*di;
  a0 += blo(v)*sc;
  a1 += bhi(v)*sc;
  float2 o; o.x = a0 + bias[2*t]; o.y = a1 + bias[2*t+1];
  *(float2*)&out[(long)d*F_H + 2*t] = o;
}

// ---------------- GraphNorm ----------------
#define STAT_ROWS 50
__global__ __launch_bounds__(512) void k_stats(const float* __restrict__ x,
    float* __restrict__ msum, float* __restrict__ ssum){
  int c = threadIdx.x;
  int r0 = blockIdx.x*STAT_ROWS;
  float s = 0.f, s2 = 0.f;
  for (int r=r0;r<r0+STAT_ROWS;r++){ float v = x[(long)r*F_H+c]; s += v; s2 += v*v; }
  atomicAdd(&msum[c], s);
  atomicAdd(&ssum[c], s2);
}
__global__ __launch_bounds__(512) void k_final(const float* __restrict__ x,
    const float* __restrict__ msum, const float* __restrict__ ssum,
    const float* __restrict__ w, const float* __restrict__ b, const float* __restrict__ a,
    const unsigned short* __restrict__ prevb, unsigned short* __restrict__ loutb,
    unsigned short* __restrict__ jkb, int mode)
{
  int c = threadIdx.x;
  float mean = msum[c]*(1.f/N_NODES);
  float aa = a[c];
  float var = ssum[c]*(1.f/N_NODES) - mean*mean*aa*(2.f-aa);
  float inv = rsqrtf(var + EPSV);
  float am = aa*mean;
  float wc = w[c], bc = b[c];
  int r0 = blockIdx.x*STAT_ROWS;
  for (int r=r0;r<r0+STAT_ROWS;r++){
    long idx = (long)r*F_H+c;
    float y = fmaxf(wc*(x[idx]-am)*inv+bc, 0.f);
    if (mode == 0) {
      unsigned short qv = f2b(y);
      loutb[idx] = qv;
      jkb[idx] = qv;
    } else if (mode == 1) {
      loutb[idx] = f2b(y + b2f(prevb[idx]));
      jkb[idx] = f2b(fmaxf(b2f(jkb[idx]), y));
    } else {
      jkb[idx] = f2b(fmaxf(b2f(jkb[idx]), y));
    }
  }
}

extern "C" void kernel_launch(void* const* d_in, const int* in_sizes, int n_in,
                              void* d_out, int out_size, void* d_ws, size_t ws_size,
                              hipStream_t stream) {
  (void)in_sizes; (void)n_in; (void)out_size; (void)ws_size;
  const float* x     = (const float*)d_in[0];
  const int*   ei    = (const int*)d_in[1];
  const int*   srcp  = ei;
  const int*   dstp  = ei + N_EDGES;
  const float* Wc[3]  = {(const float*)d_in[2], (const float*)d_in[4], (const float*)d_in[6]};
  const float* bc_[3] = {(const float*)d_in[3], (const float*)d_in[5], (const float*)d_in[7]};
  const float* lin1W = (const float*)d_in[8];
  const float* lin1b = (const float*)d_in[9];
  const float* lin2W = (const float*)d_in[10];
  const float* lin2b = (const float*)d_in[11];
  const float* gw[3] = {(const float*)d_in[12], (const float*)d_in[15], (const float*)d_in[18]};
  const float* gb[3] = {(const float*)d_in[13], (const float*)d_in[16], (const float*)d_in[19]};
  const float* ga[3] = {(const float*)d_in[14], (const float*)d_in[17], (const float*)d_in[20]};

  float* out = (float*)d_out;

  // ---- d_out scratch layout ----
  unsigned short* l0b  = (unsigned short*)(out + SZL);
  unsigned short* hinb = (unsigned short*)(out + SZL + ACT);
  unsigned short* jkb  = (unsigned short*)(out + SZL + 2*ACT);
  unsigned short* t_b  = (unsigned short*)(out + 57200000L);

  // ---- ws layout ----
  float* ws   = (float*)d_ws;
  float* agg  = ws;
  unsigned short* f1b = (unsigned short*)(ws + SZL);
  long off = SZL + ACT;
  unsigned short* W0T   = (unsigned short*)(ws + off); off += (long)F_H*KP0/2;
  unsigned short* W1T   = (unsigned short*)(ws + off); off += (long)F_H*F_H/2;
  unsigned short* W2T   = (unsigned short*)(ws + off); off += (long)F_H*F_H/2;
  unsigned short* l1WT  = (unsigned short*)(ws + off); off += (long)F_H*F_H/2;
  unsigned short* l2WT  = (unsigned short*)(ws + off); off += (long)NP2*F_H/2;
  float* dinv  = ws + off;                  off += N_NODES;
  float* stats = ws + off;                  off += 3*1024;
  int* deg    = (int*)(ws + off);           off += N_NODES;
  int* rowptr = (int*)(ws + off);           off += N_NODES + 1;
  int* cursor = (int*)(ws + off);           off += N_NODES;
  int* colsrc = (int*)(ws + off);

  // ---- CSR build ----
  k_zero_ds<<<(N_NODES+3072+255)/256,256,0,stream>>>(deg, stats);
  k_degree<<<(N_EDGES+255)/256,256,0,stream>>>(dstp, deg);
  k_scan<<<1,1024,0,stream>>>(deg, rowptr, cursor, dinv);
  k_scatter<<<(N_EDGES+255)/256,256,0,stream>>>(srcp, dstp, cursor, colsrc);

  // ---- weight conversions ----
  {
    long nAll = (long)F_H*KP0 + 3L*F_H*F_H + (long)NP2*F_H;
    k_cvtW<<<(int)((nAll+255)/256),256,0,stream>>>(Wc[0], Wc[1], Wc[2], lin1W, lin2W,
                                                   W0T, W1T, W2T, l1WT, l2WT);
  }

  // ---- 3 GCN layers ----
  for (int i = 0; i < 3; i++) {
    float* msum = stats + i*1024;
    float* ssum = msum + 512;
    if (i == 0) {
      // conv0: raw fp32 x via GLDS + in-kernel cvt (no xb pass)
      k_gbx<<<dim3(F_H/128, N_PAD/128),256,0,stream>>>(x, W0T, t_b);
    } else {
      const unsigned short* Ain = (i==1) ? l0b : hinb;
      const unsigned short* Wt  = (i==1) ? W1T : W2T;
      k_gb3<1,0><<<dim3(F_H/128, N_PAD/128),256,0,stream>>>(Ain, Wt, nullptr, t_b,
          N_NODES, F_H, F_H, F_H, F_H);
    }
    k_agg<<<N_NODES,256,0,stream>>>(t_b, rowptr, colsrc, dinv, bc_[i], agg);
    k_stats<<<N_NODES/STAT_ROWS,512,0,stream>>>(agg, msum, ssum);
    k_final<<<N_NODES/STAT_ROWS,512,0,stream>>>(agg, msum, ssum, gw[i], gb[i], ga[i],
        l0b, (i==0)? l0b : hinb, jkb, i);
  }

  // ---- head ----
  k_gb3<1,1><<<dim3(F_H/128, N_PAD/128),256,0,stream>>>(jkb, l1WT, lin1b, f1b,
      N_NODES, F_H, F_H, F_H, F_H);
  k_gb<0,0,1><<<dim3(NP2/128, N_PAD/128),256,0,stream>>>(f1b, l2WT, lin2b, out,
      N_NODES, F_IN, F_H, F_H, F_IN);
}

// Round 15
// 971.356 us; speedup vs baseline: 1.1552x; 1.1552x over previous
//
#include <hip/hip_runtime.h>

#define N_NODES 20000
#define N_PAD   20096      /* 157*128 */
#define N_EDGES 320000
#define F_IN 4644
#define KP0  4672          /* F_IN padded to 32 */
#define NP2  4736          /* F_IN padded to 128 */
#define F_H 512
#define EPSV 1e-5f
#define SZL 10240000L
#define ACT 5200000L

using short8 = __attribute__((ext_vector_type(8))) short;
using f32x4  = __attribute__((ext_vector_type(4))) float;

__device__ inline unsigned short f2b(float f){
  union{float f; unsigned u;} v; v.f=f;
  unsigned u = v.u + 0x7fffu + ((v.u>>16)&1u);
  return (unsigned short)(u>>16);
}
__device__ inline float blo(unsigned v){ return __uint_as_float(v<<16); }
__device__ inline float bhi(unsigned v){ return __uint_as_float(v & 0xffff0000u); }
__device__ inline float b2f(unsigned short v){ return __uint_as_float(((unsigned)v)<<16); }

#define GLDS(g, l) __builtin_amdgcn_global_load_lds( \
    (const __attribute__((address_space(1))) void*)(g), \
    (__attribute__((address_space(3))) void*)(l), 16, 0, 0)

// ---------------- utility / CSR ----------------
__global__ void k_zero_ds(int* __restrict__ deg, float* __restrict__ st){
  int i = blockIdx.x*blockDim.x+threadIdx.x;
  if (i < N_NODES) deg[i] = 0;
  else if (i < N_NODES + 3072) st[i - N_NODES] = 0.f;
}
__global__ void k_degree(const int* __restrict__ dst, int* __restrict__ deg){
  int e = blockIdx.x*blockDim.x+threadIdx.x;
  if (e < N_EDGES) atomicAdd(&deg[dst[e]], 1);
}
__global__ __launch_bounds__(1024) void k_scan(const int* __restrict__ deg, int* __restrict__ rowptr,
                                               int* __restrict__ cursor, float* __restrict__ dinv){
  __shared__ int sh[1024];
  int t = threadIdx.x;
  const int C = 20;
  int base = t*C;
  int loc[C];
  int s = 0;
  #pragma unroll
  for (int i=0;i<C;i++){ int idx=base+i; int v = (idx<N_NODES)?deg[idx]:0; loc[i]=s; s+=v; }
  sh[t]=s; __syncthreads();
  for (int off=1; off<1024; off<<=1){
    int v = (t>=off)?sh[t-off]:0;
    __syncthreads();
    sh[t]+=v;
    __syncthreads();
  }
  int excl = (t==0)?0:sh[t-1];
  #pragma unroll
  for (int i=0;i<C;i++){
    int idx=base+i;
    if(idx<N_NODES){
      int rv = excl+loc[i];
      rowptr[idx]=rv; cursor[idx]=rv;
      dinv[idx] = rsqrtf((float)(deg[idx]+1));
    }
  }
  if (t==1023) rowptr[N_NODES]=sh[1023];
}
__global__ void k_scatter(const int* __restrict__ src, const int* __restrict__ dst,
                          int* __restrict__ cursor, int* __restrict__ colsrc){
  int e = blockIdx.x*blockDim.x+threadIdx.x;
  if (e < N_EDGES){
    int p = atomicAdd(&cursor[dst[e]], 1);
    colsrc[p] = src[e];
  }
}

// ---------------- conversions: x + all 5 weights in ONE launch ----------------
#define NXC  ((long)N_PAD*(KP0/8))
#define BXC  ((int)((NXC+255)/256))
__global__ void k_cvt(const float* __restrict__ x, unsigned short* __restrict__ xb,
                      const float* __restrict__ W0, const float* __restrict__ W1,
                      const float* __restrict__ W2, const float* __restrict__ L1,
                      const float* __restrict__ L2,
                      unsigned short* __restrict__ W0T, unsigned short* __restrict__ W1T,
                      unsigned short* __restrict__ W2T, unsigned short* __restrict__ l1WT,
                      unsigned short* __restrict__ l2WT){
  if (blockIdx.x < BXC) {
    long id = (long)blockIdx.x*256 + threadIdx.x;
    const int CPR = KP0/8;
    if (id >= NXC) return;
    int row = (int)(id / CPR), c8 = (int)(id % CPR);
    int col = c8*8;
    short8 o;
    if (row < N_NODES && col + 8 <= F_IN) {
      const float* p = &x[(long)row*F_IN + col];
      float4 v0 = *(const float4*)p, v1 = *(const float4*)(p+4);
      o[0]=(short)f2b(v0.x); o[1]=(short)f2b(v0.y); o[2]=(short)f2b(v0.z); o[3]=(short)f2b(v0.w);
      o[4]=(short)f2b(v1.x); o[5]=(short)f2b(v1.y); o[6]=(short)f2b(v1.z); o[7]=(short)f2b(v1.w);
    } else {
      #pragma unroll
      for (int j=0;j<8;j++){
        int cc = col+j;
        float v = (row < N_NODES && cc < F_IN) ? x[(long)row*F_IN + cc] : 0.f;
        o[j] = (short)f2b(v);
      }
    }
    *(short8*)&xb[id*8] = o;
  } else {
    long t = (long)(blockIdx.x - BXC)*256 + threadIdx.x;
    const long n0 = (long)F_H*KP0;
    const long nh = (long)F_H*F_H;
    const long n2 = (long)NP2*F_H;
    if (t < n0) {
      int n = (int)(t / KP0), k = (int)(t % KP0);
      W0T[t] = f2b(k < F_IN ? W0[(long)k*F_H + n] : 0.f);
    } else if ((t -= n0) < nh) {
      int n = (int)(t / F_H), k = (int)(t % F_H);
      W1T[t] = f2b(W1[(long)k*F_H + n]);
    } else if ((t -= nh) < nh) {
      int n = (int)(t / F_H), k = (int)(t % F_H);
      W2T[t] = f2b(W2[(long)k*F_H + n]);
    } else if ((t -= nh) < nh) {
      int n = (int)(t / F_H), k = (int)(t % F_H);
      l1WT[t] = f2b(L1[(long)k*F_H + n]);
    } else if ((t -= nh) < n2) {
      int n = (int)(t / F_H), k = (int)(t % F_H);
      l2WT[t] = f2b(n < F_IN ? L2[(long)k*F_IN + n] : 0.f);
    }
  }
}

// ---------------- k_gb: 2-buffer GLDS dbuf (lin2: occupancy-sensitive grid) ----------------
// C[M,N] = A[M,K]@BT[N,K]^T. 128x128 tile, BK=32, 4 waves (2x2), 4x4 16x16x32 frags/wave.
// XCD-aware bijective swizzle (T1/m204); LDS k-slot swizzle (both-sides); LDS-transpose
// epilogue; NTS=1 nontemporal fp32 C (misaligned ldc rows -> no L2 write-allocate).
template<int OUTB, int RELU, int NTS>
__global__ __launch_bounds__(256) void k_gb(
    const unsigned short* __restrict__ A, const unsigned short* __restrict__ BT,
    const float* __restrict__ bias, void* __restrict__ Cvoid,
    int M, int N, int KP, int lda, int ldc)
{
  __shared__ unsigned short smem[4][4096];
  const int tid  = threadIdx.x;
  const int gx   = gridDim.x;
  const int nwg  = gx * gridDim.y;
  const int orig = blockIdx.x + gx * blockIdx.y;
  const int q = nwg >> 3, r = nwg & 7;
  const int xcd = orig & 7, sub = orig >> 3;
  const int wg  = (xcd < r ? xcd*(q+1) : r*(q+1) + (xcd - r)*q) + sub;
  const int bn  = (wg % gx) * 128;
  const int bm  = (wg / gx) * 128;
  const int wave = tid >> 6, lane = tid & 63;
  const int wm = (wave & 1) * 64, wn = (wave >> 1) * 64;
  const int l15 = lane & 15, l4 = lane >> 4;

  f32x4 acc[4][4];
  #pragma unroll
  for (int m=0;m<4;m++)
    #pragma unroll
    for (int n=0;n<4;n++) acc[m][n] = (f32x4){0.f,0.f,0.f,0.f};

  const int c0 = wave*64 + lane;
  const int c1 = c0 + 256;
  const long ar0 = bm + (c0 >> 2); const int as0 = ((c0 & 3) ^ ((c0 >> 3) & 3))*8;
  const long ar1 = bm + (c1 >> 2); const int as1 = ((c1 & 3) ^ ((c1 >> 3) & 3))*8;
  const long br0 = bn + (c0 >> 2);
  const long br1 = bn + (c1 >> 2);
  const int ldA0 = wave*512;
  const int ldA1 = 2048 + wave*512;
  const int kro = (l4 ^ ((l15 >> 1) & 3)) * 8;
  const int nit = KP >> 5;

  GLDS(A + ar0*lda + as0, &smem[0][ldA0]);
  GLDS(A + ar1*lda + as1, &smem[0][ldA1]);
  GLDS(BT + br0*KP + as0, &smem[2][ldA0]);
  GLDS(BT + br1*KP + as1, &smem[2][ldA1]);
  __syncthreads();

  int cur = 0;
  for (int it = 0; it < nit; ++it) {
    if (it + 1 < nit) {
      const int kn = (it+1)*32;
      GLDS(A + ar0*lda + (kn + as0), &smem[cur^1][ldA0]);
      GLDS(A + ar1*lda + (kn + as1), &smem[cur^1][ldA1]);
      GLDS(BT + br0*KP + (kn + as0), &smem[2+(cur^1)][ldA0]);
      GLDS(BT + br1*KP + (kn + as1), &smem[2+(cur^1)][ldA1]);
    }
    short8 af[4], bf[4];
    #pragma unroll
    for (int m=0;m<4;m++) af[m] = *(const short8*)&smem[cur][(wm + m*16 + l15)*32 + kro];
    #pragma unroll
    for (int n=0;n<4;n++) bf[n] = *(const short8*)&smem[2+cur][(wn + n*16 + l15)*32 + kro];
    #pragma unroll
    for (int m=0;m<4;m++)
      #pragma unroll
      for (int n=0;n<4;n++)
        acc[m][n] = __builtin_amdgcn_mfma_f32_16x16x32_bf16(af[m], bf[n], acc[m][n], 0, 0, 0);
    __syncthreads();
    cur ^= 1;
  }

  float* eb = ((float*)smem) + wave*1088;
  float* Cf = (float*)Cvoid;
  unsigned short* Cb = (unsigned short*)Cvoid;
  #pragma unroll
  for (int m=0;m<4;m++){
    #pragma unroll
    for (int n=0;n<4;n++)
      #pragma unroll
      for (int r2=0;r2<4;r2++)
        eb[(l4*4+r2)*68 + n*16 + l15] = acc[m][n][r2];
    __syncthreads();
    const int row0 = bm + wm + m*16;
    #pragma unroll
    for (int i=0;i<4;i++){
      int idx = i*64 + lane;
      int rr  = idx >> 4;
      int c4  = (idx & 15) * 4;
      int row = row0 + rr;
      int col = bn + wn + c4;
      if (row < M) {
        f32x4 v = *(f32x4*)&eb[rr*68 + c4];
        float vv[4] = {v[0], v[1], v[2], v[3]};
        if (col + 3 < N) {
          #pragma unroll
          for (int j=0;j<4;j++){
            float zz = vv[j] + (bias ? bias[col+j] : 0.f);
            vv[j] = RELU ? fmaxf(zz, 0.f) : zz;
          }
          if (OUTB) {
            unsigned short o[4] = { f2b(vv[0]), f2b(vv[1]), f2b(vv[2]), f2b(vv[3]) };
            *(uint2*)&Cb[(long)row*ldc + col] = *(uint2*)o;
          } else {
            f32x4 ov = {vv[0], vv[1], vv[2], vv[3]};
            if (NTS) __builtin_nontemporal_store(ov, (f32x4*)&Cf[(long)row*ldc + col]);
            else     *(f32x4*)&Cf[(long)row*ldc + col] = ov;
          }
        } else {
          #pragma unroll
          for (int j=0;j<4;j++){
            int cc = col + j;
            if (cc < N) {
              float zz = vv[j] + (bias ? bias[cc] : 0.f);
              if (RELU) zz = fmaxf(zz, 0.f);
              if (OUTB) Cb[(long)row*ldc + cc] = f2b(zz);
              else if (NTS) __builtin_nontemporal_store(zz, &Cf[(long)row*ldc + cc]);
              else     Cf[(long)row*ldc + cc] = zz;
            }
          }
        }
      }
    }
    __syncthreads();
  }
}

// ---------------- k_gb3: 3-buffer counted-vmcnt (grid-limited GEMMs) ----------------
template<int OUTB, int RELU>
__global__ __launch_bounds__(256) void k_gb3(
    const unsigned short* __restrict__ A, const unsigned short* __restrict__ BT,
    const float* __restrict__ bias, void* __restrict__ Cvoid,
    int M, int N, int KP, int lda, int ldc)
{
  __shared__ unsigned short smem[6][4096];
  const int tid  = threadIdx.x;
  const int gx   = gridDim.x;
  const int nwg  = gx * gridDim.y;
  const int orig = blockIdx.x + gx * blockIdx.y;
  const int q = nwg >> 3, r = nwg & 7;
  const int xcd = orig & 7, sub = orig >> 3;
  const int wg  = (xcd < r ? xcd*(q+1) : r*(q+1) + (xcd - r)*q) + sub;
  const int bn  = (wg % gx) * 128;
  const int bm  = (wg / gx) * 128;
  const int wave = tid >> 6, lane = tid & 63;
  const int wm = (wave & 1) * 64, wn = (wave >> 1) * 64;
  const int l15 = lane & 15, l4 = lane >> 4;

  f32x4 acc[4][4];
  #pragma unroll
  for (int m=0;m<4;m++)
    #pragma unroll
    for (int n=0;n<4;n++) acc[m][n] = (f32x4){0.f,0.f,0.f,0.f};

  const int c0 = wave*64 + lane;
  const int c1 = c0 + 256;
  const long ar0 = bm + (c0 >> 2); const int as0 = ((c0 & 3) ^ ((c0 >> 3) & 3))*8;
  const long ar1 = bm + (c1 >> 2); const int as1 = ((c1 & 3) ^ ((c1 >> 3) & 3))*8;
  const long br0 = bn + (c0 >> 2);
  const long br1 = bn + (c1 >> 2);
  const int ldA0 = wave*512;
  const int ldA1 = 2048 + wave*512;
  const int kro = (l4 ^ ((l15 >> 1) & 3)) * 8;
  const int nit = KP >> 5;

  GLDS(A + ar0*lda + as0, &smem[0][ldA0]);
  GLDS(A + ar1*lda + as1, &smem[0][ldA1]);
  GLDS(BT + br0*KP + as0, &smem[3][ldA0]);
  GLDS(BT + br1*KP + as1, &smem[3][ldA1]);
  if (nit > 1) {
    GLDS(A + ar0*lda + 32 + as0, &smem[1][ldA0]);
    GLDS(A + ar1*lda + 32 + as1, &smem[1][ldA1]);
    GLDS(BT + br0*KP + 32 + as0, &smem[4][ldA0]);
    GLDS(BT + br1*KP + 32 + as1, &smem[4][ldA1]);
  }

  int cur = 0, pre = 2;
  for (int it = 0; it < nit; ++it) {
    if (it + 1 < nit) asm volatile("s_waitcnt vmcnt(4)" ::: "memory");
    else              asm volatile("s_waitcnt vmcnt(0)" ::: "memory");
    __builtin_amdgcn_s_barrier();

    if (it + 2 < nit) {
      const int kn = (it+2)*32;
      GLDS(A + ar0*lda + (kn + as0), &smem[pre][ldA0]);
      GLDS(A + ar1*lda + (kn + as1), &smem[pre][ldA1]);
      GLDS(BT + br0*KP + (kn + as0), &smem[3+pre][ldA0]);
      GLDS(BT + br1*KP + (kn + as1), &smem[3+pre][ldA1]);
    }

    short8 af[4], bf[4];
    #pragma unroll
    for (int m=0;m<4;m++) af[m] = *(const short8*)&smem[cur][(wm + m*16 + l15)*32 + kro];
    #pragma unroll
    for (int n=0;n<4;n++) bf[n] = *(const short8*)&smem[3+cur][(wn + n*16 + l15)*32 + kro];
    #pragma unroll
    for (int m=0;m<4;m++)
      #pragma unroll
      for (int n=0;n<4;n++)
        acc[m][n] = __builtin_amdgcn_mfma_f32_16x16x32_bf16(af[m], bf[n], acc[m][n], 0, 0, 0);

    cur = (cur == 2) ? 0 : cur + 1;
    pre = (pre == 2) ? 0 : pre + 1;
  }
  __syncthreads();

  float* eb = ((float*)smem) + wave*1088;
  float* Cf = (float*)Cvoid;
  unsigned short* Cb = (unsigned short*)Cvoid;
  #pragma unroll
  for (int m=0;m<4;m++){
    #pragma unroll
    for (int n=0;n<4;n++)
      #pragma unroll
      for (int r2=0;r2<4;r2++)
        eb[(l4*4+r2)*68 + n*16 + l15] = acc[m][n][r2];
    __syncthreads();
    const int row0 = bm + wm + m*16;
    #pragma unroll
    for (int i=0;i<4;i++){
      int idx = i*64 + lane;
      int rr  = idx >> 4;
      int c4  = (idx & 15) * 4;
      int row = row0 + rr;
      int col = bn + wn + c4;
      if (row < M) {
        f32x4 v = *(f32x4*)&eb[rr*68 + c4];
        float vv[4] = {v[0], v[1], v[2], v[3]};
        if (col + 3 < N) {
          #pragma unroll
          for (int j=0;j<4;j++){
            float zz = vv[j] + (bias ? bias[col+j] : 0.f);
            vv[j] = RELU ? fmaxf(zz, 0.f) : zz;
          }
          if (OUTB) {
            unsigned short o[4] = { f2b(vv[0]), f2b(vv[1]), f2b(vv[2]), f2b(vv[3]) };
            *(uint2*)&Cb[(long)row*ldc + col] = *(uint2*)o;
          } else {
            *(f32x4*)&Cf[(long)row*ldc + col] = (f32x4){vv[0], vv[1], vv[2], vv[3]};
          }
        } else {
          #pragma unroll
          for (int j=0;j<4;j++){
            int cc = col + j;
            if (cc < N) {
              float zz = vv[j] + (bias ? bias[cc] : 0.f);
              if (RELU) zz = fmaxf(zz, 0.f);
              if (OUTB) Cb[(long)row*ldc + cc] = f2b(zz);
              else      Cf[(long)row*ldc + cc] = zz;
            }
          }
        }
      }
    }
    __syncthreads();
  }
}

// ---------------- GCN aggregation (bf16 h, fp32 accumulate) ----------------
__global__ __launch_bounds__(256) void k_agg(const unsigned short* __restrict__ h,
    const int* __restrict__ rowptr, const int* __restrict__ colsrc,
    const float* __restrict__ dinv, const float* __restrict__ bias,
    float* __restrict__ out)
{
  int d = blockIdx.x;
  int t = threadIdx.x;
  const unsigned* h32 = (const unsigned*)h;
  float di = dinv[d];
  int beg = rowptr[d], end = rowptr[d+1];
  float a0 = 0.f, a1 = 0.f;
  for (int e = beg; e < end; e++) {
    int s = colsrc[e];
    float cf = dinv[s]*di;
    unsigned v = h32[(long)s*256 + t];
    a0 += blo(v)*cf;
    a1 += bhi(v)*cf;
  }
  unsigned v = h32[(long)d*256 + t];
  float sc = di*di;
  a0 += blo(v)*sc;
  a1 += bhi(v)*sc;
  float2 o; o.x = a0 + bias[2*t]; o.y = a1 + bias[2*t+1];
  *(float2*)&out[(long)d*F_H + 2*t] = o;
}

// ---------------- GraphNorm ----------------
#define STAT_ROWS 50
__global__ __launch_bounds__(512) void k_stats(const float* __restrict__ x,
    float* __restrict__ msum, float* __restrict__ ssum){
  int c = threadIdx.x;
  int r0 = blockIdx.x*STAT_ROWS;
  float s = 0.f, s2 = 0.f;
  for (int r=r0;r<r0+STAT_ROWS;r++){ float v = x[(long)r*F_H+c]; s += v; s2 += v*v; }
  atomicAdd(&msum[c], s);
  atomicAdd(&ssum[c], s2);
}
// mode 0: loutb=bf16(y)                            (jkb NOT written: jk after L0 == l0b)
// mode 1: loutb=bf16(y + b2f(prevb)), jkb=max(b2f(prevb), y)   (prevb = l0b serves both)
// mode 2: jkb=max(b2f(jkb), y)
__global__ __launch_bounds__(512) void k_final(const float* __restrict__ x,
    const float* __restrict__ msum, const float* __restrict__ ssum,
    const float* __restrict__ w, const float* __restrict__ b, const float* __restrict__ a,
    const unsigned short* __restrict__ prevb, unsigned short* __restrict__ loutb,
    unsigned short* __restrict__ jkb, int mode)
{
  int c = threadIdx.x;
  float mean = msum[c]*(1.f/N_NODES);
  float aa = a[c];
  float var = ssum[c]*(1.f/N_NODES) - mean*mean*aa*(2.f-aa);
  float inv = rsqrtf(var + EPSV);
  float am = aa*mean;
  float wc = w[c], bc = b[c];
  int r0 = blockIdx.x*STAT_ROWS;
  for (int r=r0;r<r0+STAT_ROWS;r++){
    long idx = (long)r*F_H+c;
    float y = fmaxf(wc*(x[idx]-am)*inv+bc, 0.f);
    if (mode == 0) {
      loutb[idx] = f2b(y);
    } else if (mode == 1) {
      float prev = b2f(prevb[idx]);
      loutb[idx] = f2b(y + prev);
      jkb[idx] = f2b(fmaxf(prev, y));
    } else {
      jkb[idx] = f2b(fmaxf(b2f(jkb[idx]), y));
    }
  }
}

extern "C" void kernel_launch(void* const* d_in, const int* in_sizes, int n_in,
                              void* d_out, int out_size, void* d_ws, size_t ws_size,
                              hipStream_t stream) {
  (void)in_sizes; (void)n_in; (void)out_size; (void)ws_size;
  const float* x     = (const float*)d_in[0];
  const int*   ei    = (const int*)d_in[1];
  const int*   srcp  = ei;
  const int*   dstp  = ei + N_EDGES;
  const float* Wc[3]  = {(const float*)d_in[2], (const float*)d_in[4], (const float*)d_in[6]};
  const float* bc_[3] = {(const float*)d_in[3], (const float*)d_in[5], (const float*)d_in[7]};
  const float* lin1W = (const float*)d_in[8];
  const float* lin1b = (const float*)d_in[9];
  const float* lin2W = (const float*)d_in[10];
  const float* lin2b = (const float*)d_in[11];
  const float* gw[3] = {(const float*)d_in[12], (const float*)d_in[15], (const float*)d_in[18]};
  const float* gb[3] = {(const float*)d_in[13], (const float*)d_in[16], (const float*)d_in[19]};
  const float* ga[3] = {(const float*)d_in[14], (const float*)d_in[17], (const float*)d_in[20]};

  float* out = (float*)d_out;

  // ---- d_out scratch layout ----
  unsigned short* xb   = (unsigned short*)(out + SZL);
  unsigned short* l0b  = (unsigned short*)(out + SZL);
  unsigned short* hinb = (unsigned short*)(out + SZL + ACT);
  unsigned short* jkb  = (unsigned short*)(out + SZL + 2*ACT);
  unsigned short* t_b  = (unsigned short*)(out + 57200000L);

  // ---- ws layout ----
  float* ws   = (float*)d_ws;
  float* agg  = ws;
  unsigned short* f1b = (unsigned short*)(ws + SZL);
  long off = SZL + ACT;
  unsigned short* W0T   = (unsigned short*)(ws + off); off += (long)F_H*KP0/2;
  unsigned short* W1T   = (unsigned short*)(ws + off); off += (long)F_H*F_H/2;
  unsigned short* W2T   = (unsigned short*)(ws + off); off += (long)F_H*F_H/2;
  unsigned short* l1WT  = (unsigned short*)(ws + off); off += (long)F_H*F_H/2;
  unsigned short* l2WT  = (unsigned short*)(ws + off); off += (long)NP2*F_H/2;
  float* dinv  = ws + off;                  off += N_NODES;
  float* stats = ws + off;                  off += 3*1024;
  int* deg    = (int*)(ws + off);           off += N_NODES;
  int* rowptr = (int*)(ws + off);           off += N_NODES + 1;
  int* cursor = (int*)(ws + off);           off += N_NODES;
  int* colsrc = (int*)(ws + off);

  // ---- CSR build ----
  k_zero_ds<<<(N_NODES+3072+255)/256,256,0,stream>>>(deg, stats);
  k_degree<<<(N_EDGES+255)/256,256,0,stream>>>(dstp, deg);
  k_scan<<<1,1024,0,stream>>>(deg, rowptr, cursor, dinv);
  k_scatter<<<(N_EDGES+255)/256,256,0,stream>>>(srcp, dstp, cursor, colsrc);

  // ---- conversions: one launch (x + all weights) ----
  {
    long nAll = (long)F_H*KP0 + 3L*F_H*F_H + (long)NP2*F_H;
    int nblk = BXC + (int)((nAll+255)/256);
    k_cvt<<<nblk,256,0,stream>>>(x, xb, Wc[0], Wc[1], Wc[2], lin1W, lin2W,
                                 W0T, W1T, W2T, l1WT, l2WT);
  }

  // ---- 3 GCN layers ----
  for (int i = 0; i < 3; i++) {
    float* msum = stats + i*1024;
    float* ssum = msum + 512;
    if (i == 0) {
      k_gb3<1,0><<<dim3(F_H/128, N_PAD/128),256,0,stream>>>(xb, W0T, nullptr, t_b,
          N_NODES, F_H, KP0, KP0, F_H);
    } else {
      const unsigned short* Ain = (i==1) ? l0b : hinb;
      const unsigned short* Wt  = (i==1) ? W1T : W2T;
      k_gb3<1,0><<<dim3(F_H/128, N_PAD/128),256,0,stream>>>(Ain, Wt, nullptr, t_b,
          N_NODES, F_H, F_H, F_H, F_H);
    }
    k_agg<<<N_NODES,256,0,stream>>>(t_b, rowptr, colsrc, dinv, bc_[i], agg);
    k_stats<<<N_NODES/STAT_ROWS,512,0,stream>>>(agg, msum, ssum);
    k_final<<<N_NODES/STAT_ROWS,512,0,stream>>>(agg, msum, ssum, gw[i], gb[i], ga[i],
        l0b, (i==0)? l0b : hinb, jkb, i);
  }

  // ---- head ----
  k_gb3<1,1><<<dim3(F_H/128, N_PAD/128),256,0,stream>>>(jkb, l1WT, lin1b, f1b,
      N_NODES, F_H, F_H, F_H, F_H);
  k_gb<0,0,1><<<dim3(NP2/128, N_PAD/128),256,0,stream>>>(f1b, l2WT, lin2b, out,
      N_NODES, F_IN, F_H, F_H, F_IN);
}